// Round 1
// baseline (586.240 us; speedup 1.0000x reference)
//
#include <hip/hip_runtime.h>
#include <hip/hip_bf16.h>
#include <math.h>

// Problem constants (fixed by setup_inputs): B=4, H=W=128, A=1024, C=6
#define A_DIM 1024
#define C_DIM 6
#define N_PIX 65536          // B*H*W
#define HW 16384             // H*W
#define S1_BLOCKS 512        // stage-1 partial count
#define S1_ROWS 128          // rows per stage-1 block (65536/512)

// ws float layout
// [0..5]   Z[c]   (sum of exp(tarout) per class)
// [6]      loss1 accumulator
// [7]      loss2 accumulator
// [8..13]  counts[c]
// [64 ..)            Yn (6144 floats)
// [64+6144 ..)       part1 (512*6144)
// [.. +98304)        part2 (16*6144)
#define WS_ACC  0
#define WS_YN   64
#define WS_P1   (WS_YN + C_DIM * A_DIM)
#define WS_P2   (WS_P1 + S1_BLOCKS * C_DIM * A_DIM)

__global__ void k_zero(float* __restrict__ acc) {
    if (threadIdx.x < 64) acc[threadIdx.x] = 0.0f;
}

// ---- per-class masked column sums of srcfeat + label histogram ----
__global__ __launch_bounds__(256) void k_src_stage1(
        const float* __restrict__ src, const int* __restrict__ labels,
        float* __restrict__ part, float* __restrict__ counts) {
    const int t = threadIdx.x;          // 0..255
    const int g = blockIdx.x;           // 0..511
    const int row0 = g * S1_ROWS;

    float acc[C_DIM][4];
#pragma unroll
    for (int c = 0; c < C_DIM; ++c)
#pragma unroll
        for (int j = 0; j < 4; ++j) acc[c][j] = 0.0f;
    int cnt[C_DIM] = {0, 0, 0, 0, 0, 0};

#pragma unroll 2
    for (int r = 0; r < S1_ROWS; ++r) {
        const int row = row0 + r;
        const int lab = labels[row];
        const float* p = src + (size_t)row * A_DIM + t;
        float x0 = p[0];
        float x1 = p[256];
        float x2 = p[512];
        float x3 = p[768];
#pragma unroll
        for (int c = 0; c < C_DIM; ++c) {
            float m = (lab == c) ? 1.0f : 0.0f;
            acc[c][0] = fmaf(m, x0, acc[c][0]);
            acc[c][1] = fmaf(m, x1, acc[c][1]);
            acc[c][2] = fmaf(m, x2, acc[c][2]);
            acc[c][3] = fmaf(m, x3, acc[c][3]);
        }
        if (t == 0) {
#pragma unroll
            for (int c = 0; c < C_DIM; ++c) cnt[c] += (lab == c) ? 1 : 0;
        }
    }

    float* dst = part + (size_t)g * (C_DIM * A_DIM);
#pragma unroll
    for (int c = 0; c < C_DIM; ++c)
#pragma unroll
        for (int j = 0; j < 4; ++j)
            dst[c * A_DIM + j * 256 + t] = acc[c][j];

    if (t == 0) {
#pragma unroll
        for (int c = 0; c < C_DIM; ++c) atomicAdd(&counts[c], (float)cnt[c]);
    }
}

// ---- reduce 512 partials -> 16 ----
__global__ __launch_bounds__(256) void k_src_stage2a(
        const float* __restrict__ part, float* __restrict__ part2) {
    const int tid = blockIdx.x * 256 + threadIdx.x;   // 0..98303
    const int j = tid % (C_DIM * A_DIM);
    const int chunk = tid / (C_DIM * A_DIM);          // 0..15
    const float* p = part + (size_t)chunk * 32 * (C_DIM * A_DIM) + j;
    float s = 0.0f;
#pragma unroll 4
    for (int i = 0; i < 32; ++i) s += p[(size_t)i * (C_DIM * A_DIM)];
    part2[tid] = s;
}

// ---- 16 -> mean, write d_out[1..] ----
__global__ __launch_bounds__(256) void k_src_stage2b(
        const float* __restrict__ part2, const float* __restrict__ counts,
        float* __restrict__ out_mean) {
    const int j = blockIdx.x * 256 + threadIdx.x;     // 0..6143
    float s = 0.0f;
#pragma unroll
    for (int i = 0; i < 16; ++i) s += part2[i * (C_DIM * A_DIM) + j];
    const int c = j >> 10;
    out_mean[j] = s / fmaxf(counts[c], 1.0f);
}

// ---- normalize Proto rows -> Yn ----
__global__ __launch_bounds__(256) void k_proto_norm(
        const float* __restrict__ proto, float* __restrict__ yn) {
    const int c = blockIdx.x;
    const int t = threadIdx.x;
    const float* row = proto + c * A_DIM;
    float ss = 0.0f;
#pragma unroll
    for (int j = 0; j < 4; ++j) {
        float x = row[t + j * 256];
        ss = fmaf(x, x, ss);
    }
    for (int off = 32; off > 0; off >>= 1) ss += __shfl_down(ss, off, 64);
    __shared__ float sred[4];
    if ((t & 63) == 0) sred[t >> 6] = ss;
    __syncthreads();
    const float tot = sred[0] + sred[1] + sred[2] + sred[3];
    const float inv = 1.0f / fmaxf(sqrtf(tot), 1e-12f);
#pragma unroll
    for (int j = 0; j < 4; ++j) yn[c * A_DIM + t + j * 256] = row[t + j * 256] * inv;
}

// ---- per-class sum of exp(tarout) ----
__global__ __launch_bounds__(256) void k_zsum(
        const float* __restrict__ tarout, float* __restrict__ Z) {
    const int c = blockIdx.x >> 4;        // 0..5
    const int chunk = blockIdx.x & 15;    // 0..15
    const int q0 = chunk * 4096;          // stays within one batch image (4096 | 16384)
    const int t = threadIdx.x;
    const int b = q0 >> 14;
    const int hw0 = q0 & (HW - 1);
    const float* p = tarout + ((size_t)(b * C_DIM + c) << 14) + hw0;
    float s = 0.0f;
#pragma unroll
    for (int i = 0; i < 16; ++i) s += __expf(p[i * 256 + t]);
    for (int off = 32; off > 0; off >>= 1) s += __shfl_down(s, off, 64);
    __shared__ float sred[4];
    if ((t & 63) == 0) sred[t >> 6] = s;
    __syncthreads();
    if (t == 0) atomicAdd(&Z[c], sred[0] + sred[1] + sred[2] + sred[3]);
}

// ---- main: contrast + both losses ----
__global__ __launch_bounds__(256) void k_main(
        const float* __restrict__ tarfeat, const float* __restrict__ tarout,
        const float* __restrict__ yn, const float* __restrict__ Z,
        float* __restrict__ lossacc) {
    __shared__ __align__(16) float s_yn[C_DIM * A_DIM];
    __shared__ float red[7][4][64];   // [quantity][wave][pixel-lane], conflict-free

    const int t = threadIdx.x;
#pragma unroll
    for (int i = 0; i < 24; ++i) s_yn[i * 256 + t] = yn[i * 256 + t];
    __syncthreads();

    const int wave = t >> 6;
    const int lane = t & 63;
    const int p = blockIdx.x * 64 + lane;     // pixel id
    const int b = p >> 14;
    const int hw = p & (HW - 1);
    const float* xp = tarfeat + ((size_t)b << 24) + hw;   // b*A*HW + hw
    const int a0 = wave * 256;                // each wave covers 256 channels

    float ns = 0.0f;
    float d0 = 0.0f, d1 = 0.0f, d2 = 0.0f, d3 = 0.0f, d4 = 0.0f, d5 = 0.0f;
    for (int k = 0; k < 64; ++k) {
        const int a = a0 + k * 4;
        float x0 = xp[(size_t)(a + 0) << 14];
        float x1 = xp[(size_t)(a + 1) << 14];
        float x2 = xp[(size_t)(a + 2) << 14];
        float x3 = xp[(size_t)(a + 3) << 14];
        float4 y0 = *(const float4*)(s_yn + 0 * A_DIM + a);
        float4 y1 = *(const float4*)(s_yn + 1 * A_DIM + a);
        float4 y2 = *(const float4*)(s_yn + 2 * A_DIM + a);
        float4 y3 = *(const float4*)(s_yn + 3 * A_DIM + a);
        float4 y4 = *(const float4*)(s_yn + 4 * A_DIM + a);
        float4 y5 = *(const float4*)(s_yn + 5 * A_DIM + a);
        ns = fmaf(x0, x0, ns); ns = fmaf(x1, x1, ns);
        ns = fmaf(x2, x2, ns); ns = fmaf(x3, x3, ns);
        d0 = fmaf(x0, y0.x, d0); d0 = fmaf(x1, y0.y, d0); d0 = fmaf(x2, y0.z, d0); d0 = fmaf(x3, y0.w, d0);
        d1 = fmaf(x0, y1.x, d1); d1 = fmaf(x1, y1.y, d1); d1 = fmaf(x2, y1.z, d1); d1 = fmaf(x3, y1.w, d1);
        d2 = fmaf(x0, y2.x, d2); d2 = fmaf(x1, y2.y, d2); d2 = fmaf(x2, y2.z, d2); d2 = fmaf(x3, y2.w, d2);
        d3 = fmaf(x0, y3.x, d3); d3 = fmaf(x1, y3.y, d3); d3 = fmaf(x2, y3.z, d3); d3 = fmaf(x3, y3.w, d3);
        d4 = fmaf(x0, y4.x, d4); d4 = fmaf(x1, y4.y, d4); d4 = fmaf(x2, y4.z, d4); d4 = fmaf(x3, y4.w, d4);
        d5 = fmaf(x0, y5.x, d5); d5 = fmaf(x1, y5.y, d5); d5 = fmaf(x2, y5.z, d5); d5 = fmaf(x3, y5.w, d5);
    }

    red[0][wave][lane] = ns;
    red[1][wave][lane] = d0;
    red[2][wave][lane] = d1;
    red[3][wave][lane] = d2;
    red[4][wave][lane] = d3;
    red[5][wave][lane] = d4;
    red[6][wave][lane] = d5;
    __syncthreads();

    if (t < 64) {   // wave 0 finalizes the block's 64 pixels
        float v[7];
#pragma unroll
        for (int i = 0; i < 7; ++i)
            v[i] = red[i][0][t] + red[i][1][t] + red[i][2][t] + red[i][3][t];
        const float inv = 1.0f / fmaxf(sqrtf(v[0]), 1e-12f);

        const int p2 = blockIdx.x * 64 + t;
        const int bb = p2 >> 14;
        const int hw2 = p2 & (HW - 1);
        float tv[6];
#pragma unroll
        for (int c = 0; c < C_DIM; ++c)
            tv[c] = tarout[((size_t)(bb * C_DIM + c) << 14) + hw2];

        float m = tv[0];
#pragma unroll
        for (int c = 1; c < C_DIM; ++c) m = fmaxf(m, tv[c]);
        float ex[6], ssum = 0.0f;
#pragma unroll
        for (int c = 0; c < C_DIM; ++c) { ex[c] = __expf(tv[c] - m); ssum += ex[c]; }

        float l1p = 0.0f, l2p = 0.0f;
#pragma unroll
        for (int c = 0; c < C_DIM; ++c) {
            const float bc = 1.0f - v[1 + c] * inv;
            l1p = fmaf(ex[c], bc, l1p);
            // exp(tv)/Z == softmax over pixels (no max-subtract; |tarout| small)
            l2p = fmaf(__expf(tv[c]) * (1.0f / Z[c]), bc, l2p);
        }
        float l1 = l1p / ssum;
        float l2 = l2p;
        for (int off = 32; off > 0; off >>= 1) {
            l1 += __shfl_down(l1, off, 64);
            l2 += __shfl_down(l2, off, 64);
        }
        if (t == 0) {
            atomicAdd(lossacc + 0, l1);
            atomicAdd(lossacc + 1, l2);
        }
    }
}

__global__ void k_final(const float* __restrict__ acc, float* __restrict__ out) {
    if (threadIdx.x == 0)
        out[0] = acc[6] / (float)N_PIX + acc[7] / (float)C_DIM;
}

extern "C" void kernel_launch(void* const* d_in, const int* in_sizes, int n_in,
                              void* d_out, int out_size, void* d_ws, size_t ws_size,
                              hipStream_t stream) {
    const float* Proto   = (const float*)d_in[0];   // (6, 1024)
    const float* srcfeat = (const float*)d_in[1];   // (65536, 1024)
    const float* tarfeat = (const float*)d_in[2];   // (4, 1024, 128, 128)
    const float* tarout  = (const float*)d_in[3];   // (4, 6, 128, 128)
    const int*   labels  = (const int*)d_in[4];     // (65536,)
    float* out = (float*)d_out;                     // [loss, mean(6x1024)] = 6145

    float* w     = (float*)d_ws;
    float* accs  = w + WS_ACC;    // Z[6], l1, l2, counts[6]
    float* yn    = w + WS_YN;
    float* part1 = w + WS_P1;
    float* part2 = w + WS_P2;

    k_zero<<<1, 64, 0, stream>>>(accs);
    k_proto_norm<<<C_DIM, 256, 0, stream>>>(Proto, yn);
    k_zsum<<<C_DIM * 16, 256, 0, stream>>>(tarout, accs);          // Z
    k_src_stage1<<<S1_BLOCKS, 256, 0, stream>>>(srcfeat, labels, part1, accs + 8);
    k_src_stage2a<<<384, 256, 0, stream>>>(part1, part2);
    k_src_stage2b<<<24, 256, 0, stream>>>(part2, accs + 8, out + 1);
    k_main<<<N_PIX / 64, 256, 0, stream>>>(tarfeat, tarout, yn, accs, accs + 6);
    k_final<<<1, 64, 0, stream>>>(accs, out);
}